// Round 4
// baseline (224.266 us; speedup 1.0000x reference)
//
#include <hip/hip_runtime.h>
#include <hip/hip_fp16.h>

#define B_    64
#define H_    448
#define W_    448
#define OUT_  256
#define HB_   486
#define WB_   486
#define HW_   (H_*W_)        // 200704
#define OO_   (OUT_*OUT_)    // 65536
#define F4PP  (HW_/4)        // 50176 float4 per channel plane
#define F4PB  (F4PP/16)      // 3136 float4 per K1 block per plane
#define MBPS  (HW_/8)        // 25088 mask bytes per sample (bit-packed)
#define BMF4S (2*HW_/4)      // 100352 float4 per sample (bm)
#define BMF4B (BMF4S/64)     // 1568 float4 per KA block

__device__ __forceinline__ float clip01(float v) { return fminf(fmaxf(v, 0.f), 1.f); }
__device__ __forceinline__ float pmodf_(float a, float m) {
  float r = fmodf(a, m);
  return (r < 0.f) ? r + m : r;
}

struct Params {
  int minx, miny, maxx, maxy, c0, c2, usebg, Hp, Wp;
  float scX, scY, offx, szx, offy, szy;
};

// uniform per-block param recompute (compiler-scalarizable: all addresses uniform)
__device__ __forceinline__ Params make_params(const int* __restrict__ pb,
                                              const int* __restrict__ cbuf, int s) {
  int mnX = W_, mxX = -1, mnY = H_, mxY = -1;
  #pragma unroll
  for (int t = 0; t < 16; ++t) {
    int base = (s*16 + t) * 4;
    mnX = min(mnX, pb[base+0]); mxX = max(mxX, pb[base+1]);
    mnY = min(mnY, pb[base+2]); mxY = max(mxY, pb[base+3]);
  }
  if (mxY < 0) { mnY = 0; mxY = H_-1; }
  if (mxX < 0) { mnX = 0; mxX = W_-1; }
  int c0 = cbuf[s*5+0], c1 = cbuf[s*5+1], c2 = cbuf[s*5+2],
      c3 = cbuf[s*5+3], c4 = cbuf[s*5+4];
  Params P;
  P.minx = mnX; P.miny = mnY; P.maxx = mxX; P.maxy = mxY;
  P.c0 = c0; P.c2 = c2; P.usebg = (c4 > 2);
  P.Hp = mxY - mnY + 1 + c2 + c3;
  P.Wp = mxX - mnX + 1 + c0 + c1;
  P.scX = (float)P.Wp / (float)OUT_;
  P.scY = (float)P.Hp / (float)OUT_;
  P.offx = (float)(mnX - c0); P.szx = (float)P.Wp;
  P.offy = (float)(mnY - c2); P.szy = (float)P.Hp;
  return P;
}

// ---------------- K1: bit-packed mask + bbox block partials ----------------
__global__ void k1_bboxmask(const float* __restrict__ wc, unsigned char* __restrict__ maskbits,
                            int* __restrict__ pb, int useMask) {
  int blk = blockIdx.x, tid = threadIdx.x;
  int s = blk >> 4, slot = blk & 15;
  const float4* w0 = (const float4*)(wc + (size_t)s*3*HW_);
  const float4* w1 = w0 + F4PP;
  const float4* w2 = w1 + F4PP;
  unsigned char* mbs = maskbits + (size_t)s*MBPS;
  int lane = tid & 63;
  int mnX = W_, mxX = -1, mnY = H_, mxY = -1;
  for (int j = tid; j < F4PB; j += 256) {
    int i = slot*F4PB + j;
    float4 a = w0[i], b = w1[i], c = w2[i];
    int m0 = (a.x != 0.f && b.x != 0.f && c.x != 0.f);
    int m1 = (a.y != 0.f && b.y != 0.f && c.y != 0.f);
    int m2 = (a.z != 0.f && b.z != 0.f && c.z != 0.f);
    int m3 = (a.w != 0.f && b.w != 0.f && c.w != 0.f);
    if (useMask) {
      int nib = m0 | (m1<<1) | (m2<<2) | (m3<<3);
      int nxt = __shfl(nib, lane + 1, 64);
      if ((lane & 1) == 0)
        mbs[i >> 1] = (unsigned char)(nib | (nxt << 4));
    }
    if (m0 | m1 | m2 | m3) {
      int y  = i / 112;          // 112 float4 per 448-px row
      int x0 = (i - y*112) * 4;
      mnY = min(mnY, y); mxY = max(mxY, y);
      int first = m0 ? 0 : (m1 ? 1 : (m2 ? 2 : 3));
      int last  = m3 ? 3 : (m2 ? 2 : (m1 ? 1 : 0));
      mnX = min(mnX, x0 + first);
      mxX = max(mxX, x0 + last);
    }
  }
  __shared__ int sr[4][256];
  sr[0][tid]=mnX; sr[1][tid]=mxX; sr[2][tid]=mnY; sr[3][tid]=mxY;
  __syncthreads();
  for (int off = 128; off > 0; off >>= 1) {
    if (tid < off) {
      sr[0][tid] = min(sr[0][tid], sr[0][tid+off]);
      sr[1][tid] = max(sr[1][tid], sr[1][tid+off]);
      sr[2][tid] = min(sr[2][tid], sr[2][tid+off]);
      sr[3][tid] = max(sr[3][tid], sr[3][tid+off]);
    }
    __syncthreads();
  }
  if (tid == 0) {
    pb[blk*4+0] = sr[0][0]; pb[blk*4+1] = sr[1][0];
    pb[blk*4+2] = sr[2][0]; pb[blk*4+3] = sr[3][0];
  }
}

// ---------------- KA: compose (4px/thr) + brightness + gray partials + bm ----------------
__global__ __launch_bounds__(256, 2)
void ka_compose(const float* __restrict__ img, const float* __restrict__ bg,
                const float* __restrict__ wc, const unsigned char* __restrict__ maskbits,
                const float* __restrict__ bm,
                const float* __restrict__ col, const float* __restrict__ bri,
                const int* __restrict__ pb, const int* __restrict__ cbuf,
                __half* __restrict__ xh, float* __restrict__ xout,
                float* __restrict__ bmout, float* __restrict__ gpart,
                int useMask, int useHalf) {
  int tid = threadIdx.x, blk = blockIdx.x;
  int s = blk >> 6, slot = blk & 63;     // 64 blocks per sample
  Params P = make_params(pb, cbuf, s);
  float colr = col[s*3+0], colg = col[s*3+1], colb = col[s*3+2];
  float brf = bri[s];

  const float* imgb = img + (size_t)s*3*HW_;
  const float* bgb  = bg  + (size_t)s*3*HB_*WB_;
  const float* w0p  = wc  + (size_t)s*3*HW_;
  const unsigned char* mbs = maskbits + (size_t)s*MBPS;

  int p0  = slot*1024 + tid*4;     // 4 consecutive px in x
  int py  = p0 >> 8;
  int px0 = p0 & 255;

  float sy = fmaxf((py + 0.5f) * P.scY - 0.5f, 0.f);
  int   y0 = (int)sy;
  float wy = sy - (float)y0;
  y0 = min(y0, P.Hp - 1);
  int y1 = min(y0 + 1, P.Hp - 1);

  float xr[4][3];
  float gsum = 0.f;
  #pragma unroll
  for (int k = 0; k < 4; ++k) {
    int px = px0 + k;
    float sx = fmaxf((px + 0.5f) * P.scX - 0.5f, 0.f);
    int   x0 = (int)sx;
    float wx = sx - (float)x0;
    x0 = min(x0, P.Wp - 1);
    int x1 = min(x0 + 1, P.Wp - 1);

    float a00[3], a01[3], a10[3], a11[3];
    auto comp = [&](int cy, int cx, float* o) {
      int oy = cy - P.c2 + P.miny;
      int ox = cx - P.c0 + P.minx;
      bool valid = (oy >= P.miny) && (oy <= P.maxy) &&
                   (ox >= P.minx) && (ox <= P.maxx);
      float mval = 0.f;
      if (valid) {
        int mi = oy * W_ + ox;
        if (useMask) mval = (float)((mbs[mi >> 3] >> (mi & 7)) & 1);
        else mval = (w0p[mi] != 0.f && w0p[mi+HW_] != 0.f && w0p[mi+2*HW_] != 0.f) ? 1.f : 0.f;
      }
      float br_, bgv_, bb_;
      if (P.usebg) {
        int byy = min(cy, HB_-1), bxx = min(cx, WB_-1);
        size_t bo = (size_t)byy * WB_ + bxx;
        br_  = bgb[bo];
        bgv_ = bgb[bo + (size_t)HB_*WB_];
        bb_  = bgb[bo + 2*(size_t)HB_*WB_];
      } else { br_ = colr; bgv_ = colg; bb_ = colb; }
      float w1m = 1.f - mval;
      float ir = 0.f, ig = 0.f, ib = 0.f;
      if (mval != 0.f) {
        size_t io = (size_t)oy * W_ + ox;
        ir = imgb[io]; ig = imgb[io + HW_]; ib = imgb[io + 2*HW_];
      }
      o[0] = ir + br_  * w1m;
      o[1] = ig + bgv_ * w1m;
      o[2] = ib + bb_  * w1m;
    };
    comp(y0, x0, a00); comp(y0, x1, a01); comp(y1, x0, a10); comp(y1, x1, a11);

    #pragma unroll
    for (int ch = 0; ch < 3; ++ch) {
      float top = a00[ch] * (1.f - wx) + a01[ch] * wx;
      float bot = a10[ch] * (1.f - wx) + a11[ch] * wx;
      float o = top * (1.f - wy) + bot * wy;
      xr[k][ch] = clip01(o * brf);
    }
    gsum += 0.299f*xr[k][0] + 0.587f*xr[k][1] + 0.114f*xr[k][2];
  }

  #pragma unroll
  for (int ch = 0; ch < 3; ++ch) {
    size_t base = (size_t)(s*3 + ch)*OO_ + p0;
    if (useHalf) {
      __half2 h01 = __floats2half2_rn(xr[0][ch], xr[1][ch]);
      __half2 h23 = __floats2half2_rn(xr[2][ch], xr[3][ch]);
      uint2 u = make_uint2(*(unsigned*)&h01, *(unsigned*)&h23);
      ((uint2*)xh)[base >> 2] = u;
    } else {
      ((float4*)xout)[base >> 2] =
        make_float4(xr[0][ch], xr[1][ch], xr[2][ch], xr[3][ch]);
    }
  }

  __shared__ float sf[256];
  sf[tid] = gsum;
  __syncthreads();
  for (int off = 128; off > 0; off >>= 1) {
    if (tid < off) sf[tid] += sf[tid+off];
    __syncthreads();
  }
  if (tid == 0) gpart[blk] = sf[0];

  // ----- bm slice (pure streaming, overlaps the gather latency above) -----
  const float4* bm4  = (const float4*)(bm    + (size_t)s*2*HW_);
  float4*       out4 = (float4*)      (bmout + (size_t)s*2*HW_);
  for (int j = tid; j < BMF4B; j += 256) {
    int idx = slot*BMF4B + j;
    float off_ = (idx < F4PP) ? P.offx : P.offy;
    float inv  = 2.f / ((idx < F4PP) ? P.szx : P.szy);
    float4 v = bm4[idx];
    float4 o;
    o.x = (v.x - off_) * inv - 1.f;
    o.y = (v.y - off_) * inv - 1.f;
    o.z = (v.z - off_) * inv - 1.f;
    o.w = (v.w - off_) * inv - 1.f;
    out4[idx] = o;
  }
}

// ---------------- KB: mean + contrast/saturation/hue, 4 px/thread ----------------
__global__ void kb_color(const __half* __restrict__ xh, const float* __restrict__ gpart,
                         const float* __restrict__ con, const float* __restrict__ sat,
                         const float* __restrict__ hue, float* __restrict__ xout,
                         int useHalf) {
  int tid = threadIdx.x, blk = blockIdx.x;
  int s = blk >> 6, slot = blk & 63;
  int u = slot*256 + tid;           // 4-px unit within plane [0, 16384)

  float sum = 0.f;
  #pragma unroll
  for (int t = 0; t < 64; ++t) sum += gpart[s*64 + t];
  float mean = sum * (1.f / (float)OO_);
  float cf = con[s], sfc = sat[s], hu = hue[s];

  float in[3][4];
  #pragma unroll
  for (int ch = 0; ch < 3; ++ch) {
    size_t base = (size_t)(s*3 + ch)*OO_ + (size_t)u*4;
    if (useHalf) {
      uint2 q = ((const uint2*)xh)[base >> 2];
      __half2 h01 = *(__half2*)&q.x;
      __half2 h23 = *(__half2*)&q.y;
      float2 f01 = __half22float2(h01);
      float2 f23 = __half22float2(h23);
      in[ch][0]=f01.x; in[ch][1]=f01.y; in[ch][2]=f23.x; in[ch][3]=f23.y;
    } else {
      float4 f = ((const float4*)xout)[base >> 2];
      in[ch][0]=f.x; in[ch][1]=f.y; in[ch][2]=f.z; in[ch][3]=f.w;
    }
  }

  float ro[4], go[4], bo[4];
  #pragma unroll
  for (int l = 0; l < 4; ++l) {
    float r = in[0][l], g = in[1][l], bl = in[2][l];
    r  = clip01(cf*r  + (1.f-cf)*mean);
    g  = clip01(cf*g  + (1.f-cf)*mean);
    bl = clip01(cf*bl + (1.f-cf)*mean);

    float gr = 0.299f*r + 0.587f*g + 0.114f*bl;
    r  = clip01(sfc*r  + (1.f-sfc)*gr);
    g  = clip01(sfc*g  + (1.f-sfc)*gr);
    bl = clip01(sfc*bl + (1.f-sfc)*gr);

    const float eps = 1e-8f;
    float mx = fmaxf(r, fmaxf(g, bl));
    float mn = fminf(r, fminf(g, bl));
    float d  = mx - mn;
    float inv = 1.f / (d + eps);
    float h;
    if (mx == r)      h = pmodf_((g - bl) * inv, 6.f);
    else if (mx == g) h = (bl - r) * inv + 2.f;
    else              h = (r - g) * inv + 4.f;
    h *= (1.f/6.f);
    if (d <= eps) h = 0.f;
    float sv = d / (mx + eps);
    float v  = mx;

    h = pmodf_(h + hu, 1.f);

    float h6 = pmodf_(h, 1.f) * 6.f;
    float fi = floorf(h6);
    float f  = h6 - fi;
    int   i6 = ((int)fi) % 6;
    float pp = v * (1.f - sv);
    float q  = v * (1.f - f*sv);
    float t  = v * (1.f - (1.f - f)*sv);
    float rr, gg, bb;
    switch (i6) {
      case 0:  rr=v;  gg=t;  bb=pp; break;
      case 1:  rr=q;  gg=v;  bb=pp; break;
      case 2:  rr=pp; gg=v;  bb=t;  break;
      case 3:  rr=pp; gg=q;  bb=v;  break;
      case 4:  rr=t;  gg=pp; bb=v;  break;
      default: rr=v;  gg=pp; bb=q;  break;
    }
    ro[l] = clip01(rr); go[l] = clip01(gg); bo[l] = clip01(bb);
  }
  size_t ub = (size_t)(s*3)*OO_ + (size_t)u*4;
  ((float4*)xout)[(ub)                >> 2] = make_float4(ro[0],ro[1],ro[2],ro[3]);
  ((float4*)xout)[(ub +   (size_t)OO_) >> 2] = make_float4(go[0],go[1],go[2],go[3]);
  ((float4*)xout)[(ub + 2*(size_t)OO_) >> 2] = make_float4(bo[0],bo[1],bo[2],bo[3]);
}

extern "C" void kernel_launch(void* const* d_in, const int* in_sizes, int n_in,
                              void* d_out, int out_size, void* d_ws, size_t ws_size,
                              hipStream_t stream) {
  const float* img = (const float*)d_in[0];
  const float* wc  = (const float*)d_in[1];
  const float* bm  = (const float*)d_in[2];
  const float* bg  = (const float*)d_in[3];
  const float* col = (const float*)d_in[4];
  const float* bri = (const float*)d_in[5];
  const float* con = (const float*)d_in[6];
  const float* sat = (const float*)d_in[7];
  const float* hue = (const float*)d_in[8];
  const int*   cb  = (const int*)d_in[9];

  float* outx  = (float*)d_out;
  float* outbm = outx + (size_t)B_*3*OO_;

  char* ws = (char*)d_ws;
  int*   pb    = (int*)ws;                                  // [0, 16384)
  float* gpart = (float*)(ws + 16384);                      // [16384, 32768)
  unsigned char* maskbits = (unsigned char*)(ws + 32768);   // 1,605,632 B
  __half* xh = (__half*)(ws + 1638400 + 2048);              // 25,165,824 B

  size_t needMask = 32768 + (size_t)B_*MBPS;                // ~1.64 MB
  size_t needHalf = 1638400 + 2048 + (size_t)B_*3*OO_*2;    // ~26.8 MB
  int useMask = (ws_size >= needMask) ? 1 : 0;
  int useHalf = (ws_size >= needHalf) ? 1 : 0;

  k1_bboxmask<<<1024, 256, 0, stream>>>(wc, maskbits, pb, useMask);
  ka_compose <<<4096, 256, 0, stream>>>(img, bg, wc, maskbits, bm, col, bri,
                                        pb, cb, xh, outx, outbm, gpart,
                                        useMask, useHalf);
  kb_color   <<<4096, 256, 0, stream>>>(xh, gpart, con, sat, hue, outx, useHalf);
}

// Round 5
// 195.923 us; speedup vs baseline: 1.1447x; 1.1447x over previous
//
#include <hip/hip_runtime.h>
#include <hip/hip_fp16.h>

#define B_    64
#define H_    448
#define W_    448
#define OUT_  256
#define HB_   486
#define WB_   486
#define HW_   (H_*W_)        // 200704
#define OO_   (OUT_*OUT_)    // 65536
#define F4PP  (HW_/4)        // 50176 float4 per channel plane
#define F4PB  (F4PP/16)      // 3136 float4 per K1 block per plane
#define MBPS  (HW_/8)        // 25088 mask bytes per sample (bit-packed)
#define BMF4S (2*HW_/4)      // 100352 float4 per sample (bm)
#define BMF4B (BMF4S/32)     // 3136 float4 per K4 block

__device__ __forceinline__ float clip01(float v) { return fminf(fmaxf(v, 0.f), 1.f); }
__device__ __forceinline__ float pmodf_(float a, float m) {
  float r = fmodf(a, m);
  return (r < 0.f) ? r + m : r;
}

struct Params {
  int minx, miny, maxx, maxy, c0, c2, usebg, Hp, Wp;
  float scX, scY, offx, szx, offy, szy;
};

// uniform per-block param recompute (all addresses uniform -> scalar loads)
__device__ __forceinline__ Params make_params(const int* __restrict__ pb,
                                              const int* __restrict__ cbuf, int s) {
  int mnX = W_, mxX = -1, mnY = H_, mxY = -1;
  #pragma unroll
  for (int t = 0; t < 16; ++t) {
    int base = (s*16 + t) * 4;
    mnX = min(mnX, pb[base+0]); mxX = max(mxX, pb[base+1]);
    mnY = min(mnY, pb[base+2]); mxY = max(mxY, pb[base+3]);
  }
  if (mxY < 0) { mnY = 0; mxY = H_-1; }
  if (mxX < 0) { mnX = 0; mxX = W_-1; }
  int c0 = cbuf[s*5+0], c1 = cbuf[s*5+1], c2 = cbuf[s*5+2],
      c3 = cbuf[s*5+3], c4 = cbuf[s*5+4];
  Params P;
  P.minx = mnX; P.miny = mnY; P.maxx = mxX; P.maxy = mxY;
  P.c0 = c0; P.c2 = c2; P.usebg = (c4 > 2);
  P.Hp = mxY - mnY + 1 + c2 + c3;
  P.Wp = mxX - mnX + 1 + c0 + c1;
  P.scX = (float)P.Wp / (float)OUT_;
  P.scY = (float)P.Hp / (float)OUT_;
  P.offx = (float)(mnX - c0); P.szx = (float)P.Wp;
  P.offy = (float)(mnY - c2); P.szy = (float)P.Hp;
  return P;
}

// ---------------- K1: bit-packed mask + bbox block partials ----------------
__global__ void k1_bboxmask(const float* __restrict__ wc, unsigned char* __restrict__ maskbits,
                            int* __restrict__ pb, int useMask) {
  int blk = blockIdx.x, tid = threadIdx.x;
  int s = blk >> 4, slot = blk & 15;
  const float4* w0 = (const float4*)(wc + (size_t)s*3*HW_);
  const float4* w1 = w0 + F4PP;
  const float4* w2 = w1 + F4PP;
  unsigned char* mbs = maskbits + (size_t)s*MBPS;
  int lane = tid & 63;
  int mnX = W_, mxX = -1, mnY = H_, mxY = -1;
  for (int j = tid; j < F4PB; j += 256) {
    int i = slot*F4PB + j;
    float4 a = w0[i], b = w1[i], c = w2[i];
    int m0 = (a.x != 0.f && b.x != 0.f && c.x != 0.f);
    int m1 = (a.y != 0.f && b.y != 0.f && c.y != 0.f);
    int m2 = (a.z != 0.f && b.z != 0.f && c.z != 0.f);
    int m3 = (a.w != 0.f && b.w != 0.f && c.w != 0.f);
    if (useMask) {
      int nib = m0 | (m1<<1) | (m2<<2) | (m3<<3);
      int nxt = __shfl(nib, lane + 1, 64);
      if ((lane & 1) == 0)
        mbs[i >> 1] = (unsigned char)(nib | (nxt << 4));
    }
    if (m0 | m1 | m2 | m3) {
      int y  = i / 112;          // 112 float4 per 448-px row
      int x0 = (i - y*112) * 4;
      mnY = min(mnY, y); mxY = max(mxY, y);
      int first = m0 ? 0 : (m1 ? 1 : (m2 ? 2 : 3));
      int last  = m3 ? 3 : (m2 ? 2 : (m1 ? 1 : 0));
      mnX = min(mnX, x0 + first);
      mxX = max(mxX, x0 + last);
    }
  }
  __shared__ int sr[4][256];
  sr[0][tid]=mnX; sr[1][tid]=mxX; sr[2][tid]=mnY; sr[3][tid]=mxY;
  __syncthreads();
  for (int off = 128; off > 0; off >>= 1) {
    if (tid < off) {
      sr[0][tid] = min(sr[0][tid], sr[0][tid+off]);
      sr[1][tid] = max(sr[1][tid], sr[1][tid+off]);
      sr[2][tid] = min(sr[2][tid], sr[2][tid+off]);
      sr[3][tid] = max(sr[3][tid], sr[3][tid+off]);
    }
    __syncthreads();
  }
  if (tid == 0) {
    pb[blk*4+0] = sr[0][0]; pb[blk*4+1] = sr[1][0];
    pb[blk*4+2] = sr[2][0]; pb[blk*4+3] = sr[3][0];
  }
}

// ---------------- K2: compose + brightness + gray partials (1 px/thread) ----------------
__global__ void k2_compose(const float* __restrict__ img, const float* __restrict__ bg,
                           const float* __restrict__ wc, const unsigned char* __restrict__ maskbits,
                           const float* __restrict__ col, const float* __restrict__ bri,
                           const int* __restrict__ pb, const int* __restrict__ cbuf,
                           __half* __restrict__ xh, float* __restrict__ xout,
                           float* __restrict__ gpart, int useMask, int useHalf) {
  int tid = threadIdx.x, blk = blockIdx.x;
  int s = blk >> 8;                 // 256 blocks per sample (one row each)
  int p = ((blk & 255) << 8) | tid; // pixel in plane
  int py = p >> 8, px = p & 255;

  Params P = make_params(pb, cbuf, s);
  float colr = col[s*3+0], colg = col[s*3+1], colb = col[s*3+2];
  float brf = bri[s];

  float sy = fmaxf((py + 0.5f) * P.scY - 0.5f, 0.f);
  int   y0 = (int)sy;
  float wy = sy - (float)y0;
  y0 = min(y0, P.Hp - 1);
  int y1 = min(y0 + 1, P.Hp - 1);

  float sx = fmaxf((px + 0.5f) * P.scX - 0.5f, 0.f);
  int   x0 = (int)sx;
  float wx = sx - (float)x0;
  x0 = min(x0, P.Wp - 1);
  int x1 = min(x0 + 1, P.Wp - 1);

  const float* imgb = img + (size_t)s*3*HW_;
  const float* bgb  = bg  + (size_t)s*3*HB_*WB_;
  const float* w0p  = wc  + (size_t)s*3*HW_;
  const unsigned char* mbs = maskbits + (size_t)s*MBPS;

  float a00[3], a01[3], a10[3], a11[3];
  // branchless: clamp coords, load unconditionally, scale by mval
  auto comp = [&](int cy, int cx, float* o) {
    int oy = cy - P.c2 + P.miny;
    int ox = cx - P.c0 + P.minx;
    bool valid = (oy >= P.miny) && (oy <= P.maxy) &&
                 (ox >= P.minx) && (ox <= P.maxx);
    int oyc = min(max(oy, 0), H_-1);
    int oxc = min(max(ox, 0), W_-1);
    int mi = oyc * W_ + oxc;
    float mval;
    if (useMask) mval = (float)((mbs[mi >> 3] >> (mi & 7)) & 1);
    else mval = (w0p[mi] != 0.f && w0p[mi+HW_] != 0.f && w0p[mi+2*HW_] != 0.f) ? 1.f : 0.f;
    if (!valid) mval = 0.f;
    size_t io = (size_t)mi;
    float ir = imgb[io], ig = imgb[io + HW_], ib = imgb[io + 2*HW_];
    float br_, bgv_, bb_;
    if (P.usebg) {   // uniform per sample
      int byy = min(cy, HB_-1), bxx = min(cx, WB_-1);
      size_t bo = (size_t)byy * WB_ + bxx;
      br_  = bgb[bo];
      bgv_ = bgb[bo + (size_t)HB_*WB_];
      bb_  = bgb[bo + 2*(size_t)HB_*WB_];
    } else { br_ = colr; bgv_ = colg; bb_ = colb; }
    float w1m = 1.f - mval;
    o[0] = ir * mval + br_  * w1m;
    o[1] = ig * mval + bgv_ * w1m;
    o[2] = ib * mval + bb_  * w1m;
  };
  comp(y0, x0, a00); comp(y0, x1, a01); comp(y1, x0, a10); comp(y1, x1, a11);

  float xr[3];
  #pragma unroll
  for (int ch = 0; ch < 3; ++ch) {
    float top = a00[ch] * (1.f - wx) + a01[ch] * wx;
    float bot = a10[ch] * (1.f - wx) + a11[ch] * wx;
    float o = top * (1.f - wy) + bot * wy;
    xr[ch] = clip01(o * brf);
    size_t oi = (size_t)(s*3 + ch)*OO_ + p;
    if (useHalf) xh[oi] = __float2half(xr[ch]);
    else         xout[oi] = xr[ch];
  }
  float gray = 0.299f*xr[0] + 0.587f*xr[1] + 0.114f*xr[2];

  __shared__ float sf[256];
  sf[tid] = gray;
  __syncthreads();
  for (int off = 128; off > 0; off >>= 1) {
    if (tid < off) sf[tid] += sf[tid+off];
    __syncthreads();
  }
  if (tid == 0) gpart[blk] = sf[0];
}

// ---------------- K4: bm affine remap (32 blocks/sample, streaming) ----------------
__global__ void k4_bm(const float* __restrict__ bm, const int* __restrict__ pb,
                      const int* __restrict__ cbuf, float* __restrict__ outp) {
  int blk = blockIdx.x, tid = threadIdx.x;
  int s = blk >> 5, slot = blk & 31;
  Params P = make_params(pb, cbuf, s);
  const float4* bm4  = (const float4*)(bm   + (size_t)s*2*HW_);
  float4*       out4 = (float4*)      (outp + (size_t)s*2*HW_);
  float invx = 2.f / P.szx, invy = 2.f / P.szy;
  for (int j = tid; j < BMF4B; j += 256) {
    int idx = slot*BMF4B + j;
    float off_ = (idx < F4PP) ? P.offx : P.offy;
    float inv  = (idx < F4PP) ? invx  : invy;
    float4 v = bm4[idx];
    float4 o;
    o.x = (v.x - off_) * inv - 1.f;
    o.y = (v.y - off_) * inv - 1.f;
    o.z = (v.z - off_) * inv - 1.f;
    o.w = (v.w - off_) * inv - 1.f;
    out4[idx] = o;
  }
}

// ---------------- KB: mean + contrast/saturation/hue, 4 px/thread ----------------
__global__ void kb_color(const __half* __restrict__ xh, const float* __restrict__ gpart,
                         const float* __restrict__ con, const float* __restrict__ sat,
                         const float* __restrict__ hue, float* __restrict__ xout,
                         int useHalf) {
  int tid = threadIdx.x, blk = blockIdx.x;
  int s = blk >> 6, slot = blk & 63;
  int u = slot*256 + tid;           // 4-px unit within plane [0, 16384)

  float sum = 0.f;
  #pragma unroll
  for (int t = 0; t < 256; ++t) sum += gpart[s*256 + t];
  float mean = sum * (1.f / (float)OO_);
  float cf = con[s], sfc = sat[s], hu = hue[s];

  float in[3][4];
  #pragma unroll
  for (int ch = 0; ch < 3; ++ch) {
    size_t base = (size_t)(s*3 + ch)*OO_ + (size_t)u*4;
    if (useHalf) {
      uint2 q = ((const uint2*)xh)[base >> 2];
      __half2 h01 = *(__half2*)&q.x;
      __half2 h23 = *(__half2*)&q.y;
      float2 f01 = __half22float2(h01);
      float2 f23 = __half22float2(h23);
      in[ch][0]=f01.x; in[ch][1]=f01.y; in[ch][2]=f23.x; in[ch][3]=f23.y;
    } else {
      float4 f = ((const float4*)xout)[base >> 2];
      in[ch][0]=f.x; in[ch][1]=f.y; in[ch][2]=f.z; in[ch][3]=f.w;
    }
  }

  float ro[4], go[4], bo[4];
  #pragma unroll
  for (int l = 0; l < 4; ++l) {
    float r = in[0][l], g = in[1][l], bl = in[2][l];
    r  = clip01(cf*r  + (1.f-cf)*mean);
    g  = clip01(cf*g  + (1.f-cf)*mean);
    bl = clip01(cf*bl + (1.f-cf)*mean);

    float gr = 0.299f*r + 0.587f*g + 0.114f*bl;
    r  = clip01(sfc*r  + (1.f-sfc)*gr);
    g  = clip01(sfc*g  + (1.f-sfc)*gr);
    bl = clip01(sfc*bl + (1.f-sfc)*gr);

    const float eps = 1e-8f;
    float mx = fmaxf(r, fmaxf(g, bl));
    float mn = fminf(r, fminf(g, bl));
    float d  = mx - mn;
    float inv = 1.f / (d + eps);
    float h;
    if (mx == r)      h = pmodf_((g - bl) * inv, 6.f);
    else if (mx == g) h = (bl - r) * inv + 2.f;
    else              h = (r - g) * inv + 4.f;
    h *= (1.f/6.f);
    if (d <= eps) h = 0.f;
    float sv = d / (mx + eps);
    float v  = mx;

    h = pmodf_(h + hu, 1.f);

    float h6 = pmodf_(h, 1.f) * 6.f;
    float fi = floorf(h6);
    float f  = h6 - fi;
    int   i6 = ((int)fi) % 6;
    float pp = v * (1.f - sv);
    float q  = v * (1.f - f*sv);
    float t  = v * (1.f - (1.f - f)*sv);
    float rr, gg, bb;
    switch (i6) {
      case 0:  rr=v;  gg=t;  bb=pp; break;
      case 1:  rr=q;  gg=v;  bb=pp; break;
      case 2:  rr=pp; gg=v;  bb=t;  break;
      case 3:  rr=pp; gg=q;  bb=v;  break;
      case 4:  rr=t;  gg=pp; bb=v;  break;
      default: rr=v;  gg=pp; bb=q;  break;
    }
    ro[l] = clip01(rr); go[l] = clip01(gg); bo[l] = clip01(bb);
  }
  size_t ub = (size_t)(s*3)*OO_ + (size_t)u*4;
  ((float4*)xout)[(ub)                 >> 2] = make_float4(ro[0],ro[1],ro[2],ro[3]);
  ((float4*)xout)[(ub +   (size_t)OO_) >> 2] = make_float4(go[0],go[1],go[2],go[3]);
  ((float4*)xout)[(ub + 2*(size_t)OO_) >> 2] = make_float4(bo[0],bo[1],bo[2],bo[3]);
}

extern "C" void kernel_launch(void* const* d_in, const int* in_sizes, int n_in,
                              void* d_out, int out_size, void* d_ws, size_t ws_size,
                              hipStream_t stream) {
  const float* img = (const float*)d_in[0];
  const float* wc  = (const float*)d_in[1];
  const float* bm  = (const float*)d_in[2];
  const float* bg  = (const float*)d_in[3];
  const float* col = (const float*)d_in[4];
  const float* bri = (const float*)d_in[5];
  const float* con = (const float*)d_in[6];
  const float* sat = (const float*)d_in[7];
  const float* hue = (const float*)d_in[8];
  const int*   cb  = (const int*)d_in[9];

  float* outx  = (float*)d_out;
  float* outbm = outx + (size_t)B_*3*OO_;

  char* ws = (char*)d_ws;
  int*   pb    = (int*)ws;                                  // [0, 16384)
  float* gpart = (float*)(ws + 16384);                      // 16384 blocks * 4B = 65536
  unsigned char* maskbits = (unsigned char*)(ws + 86016);   // 1,605,632 B
  __half* xh = (__half*)(ws + 1695744);                     // 25,165,824 B

  size_t needMask = 86016 + (size_t)B_*MBPS;
  size_t needHalf = 1695744 + (size_t)B_*3*OO_*2;
  int useMask = (ws_size >= needMask) ? 1 : 0;
  int useHalf = (ws_size >= needHalf) ? 1 : 0;

  k1_bboxmask<<<1024,  256, 0, stream>>>(wc, maskbits, pb, useMask);
  k2_compose <<<16384, 256, 0, stream>>>(img, bg, wc, maskbits, col, bri, pb, cb,
                                         xh, outx, gpart, useMask, useHalf);
  k4_bm      <<<2048,  256, 0, stream>>>(bm, pb, cb, outbm);
  kb_color   <<<4096,  256, 0, stream>>>(xh, gpart, con, sat, hue, outx, useHalf);
}